// Round 1
// baseline (754.042 us; speedup 1.0000x reference)
//
#include <hip/hip_runtime.h>
#include <math.h>

// YOLOv5 head: per scale s, y[b,o,hw] = sum_c p[b,c,hw]*w[o,c] + bias[o]
// o = a*85 + oo (a = anchor idx, oo = output idx), then sigmoid decode:
//   oo==0: (2s + gx - 0.5)*stride      gx = hw % nx
//   oo==1: (2s + gy - 0.5)*stride      gy = hw / nx
//   oo==2: (2s)^2 * anchor_w
//   oo==3: (2s)^2 * anchor_h
//   else : s
// Output layout: out[b, row, oo], row = scale_row_off + a*HW + hw, 25200 rows/batch.

#define NOUT 85
#define TOTAL_ROWS 25200

template <int C, int THW>
__global__ __launch_bounds__(256) void yolo_scale_kernel(
    const float* __restrict__ p,        // [bs, C, HW]
    const float* __restrict__ w,        // [255, C]
    const float* __restrict__ bias,     // [255]
    const float* __restrict__ anchors,  // pre-offset: [3,2] for this scale
    float* __restrict__ out,            // [bs, 25200, 85]
    int nx, int HW, int row_off, float stride_)
{
    __shared__ float p_lds[64][THW];

    const int tid = threadIdx.x;
    const int hw0 = blockIdx.x * THW;
    const int b   = blockIdx.y;

    const float* pb = p + (size_t)b * C * HW + hw0;
    // tid==255 is a pad channel: compute garbage using row 0, never stored.
    const float* wrow = w + (size_t)(tid < 255 ? tid : 0) * C;

    float acc[THW];
#pragma unroll
    for (int j = 0; j < THW; ++j) acc[j] = 0.f;

    constexpr int VPT = (64 * THW) / (256 * 4);  // float4 loads per thread per chunk

    for (int c0 = 0; c0 < C; c0 += 64) {
        __syncthreads();
        // stage p[c0..c0+63, hw0..hw0+THW-1] into LDS
#pragma unroll
        for (int v = 0; v < VPT; ++v) {
            int f0 = (v * 256 + tid) * 4;
            int cc = f0 / THW;
            int j  = f0 % THW;
            float4 pv = *reinterpret_cast<const float4*>(pb + (size_t)(c0 + cc) * HW + j);
            *reinterpret_cast<float4*>(&p_lds[cc][j]) = pv;
        }
        __syncthreads();

        for (int cc = 0; cc < 64; cc += 4) {
            float4 wv = *reinterpret_cast<const float4*>(wrow + c0 + cc);
            float wq[4] = {wv.x, wv.y, wv.z, wv.w};
#pragma unroll
            for (int u = 0; u < 4; ++u) {
                float wc = wq[u];
#pragma unroll
                for (int j = 0; j < THW; j += 4) {
                    // wave-uniform address -> LDS broadcast (conflict-free)
                    float4 pv = *reinterpret_cast<const float4*>(&p_lds[cc + u][j]);
                    acc[j + 0] += wc * pv.x;
                    acc[j + 1] += wc * pv.y;
                    acc[j + 2] += wc * pv.z;
                    acc[j + 3] += wc * pv.w;
                }
            }
        }
    }

    if (tid < 255) {
        const int a  = tid / NOUT;
        const int oo = tid % NOUT;
        const float bi = bias[tid];
        const float aw = anchors[a * 2 + 0];
        const float ah = anchors[a * 2 + 1];

#pragma unroll
        for (int j = 0; j < THW; ++j) {
            const int hw = hw0 + j;
            const float y = acc[j] + bi;
            const float s = 1.f / (1.f + __expf(-y));
            float v;
            if (oo == 0) {
                const int gx = hw % nx;
                v = (2.f * s + (float)gx - 0.5f) * stride_;
            } else if (oo == 1) {
                const int gy = hw / nx;
                v = (2.f * s + (float)gy - 0.5f) * stride_;
            } else if (oo == 2) {
                const float t2 = 2.f * s;
                v = t2 * t2 * aw;
            } else if (oo == 3) {
                const float t2 = 2.f * s;
                v = t2 * t2 * ah;
            } else {
                v = s;
            }
            const size_t row = (size_t)b * TOTAL_ROWS + row_off + (size_t)a * HW + hw;
            out[row * NOUT + oo] = v;
        }
    }
}

extern "C" void kernel_launch(void* const* d_in, const int* in_sizes, int n_in,
                              void* d_out, int out_size, void* d_ws, size_t ws_size,
                              hipStream_t stream) {
    const float* p0 = (const float*)d_in[0];
    const float* p1 = (const float*)d_in[1];
    const float* p2 = (const float*)d_in[2];
    const float* w0 = (const float*)d_in[3];
    const float* b0 = (const float*)d_in[4];
    const float* w1 = (const float*)d_in[5];
    const float* b1 = (const float*)d_in[6];
    const float* w2 = (const float*)d_in[7];
    const float* b2 = (const float*)d_in[8];
    const float* anc = (const float*)d_in[9];  // [3,3,2]
    float* out = (float*)d_out;

    const int bs = 16;
    dim3 blk(256);

    // scale 0: C=256, 80x80, stride 8
    yolo_scale_kernel<256, 32><<<dim3(6400 / 32, bs), blk, 0, stream>>>(
        p0, w0, b0, anc + 0, out, 80, 6400, 0, 8.f);
    // scale 1: C=512, 40x40, stride 16
    yolo_scale_kernel<512, 32><<<dim3(1600 / 32, bs), blk, 0, stream>>>(
        p1, w1, b1, anc + 6, out, 40, 1600, 19200, 16.f);
    // scale 2: C=1024, 20x20, stride 32
    yolo_scale_kernel<1024, 16><<<dim3(400 / 16, bs), blk, 0, stream>>>(
        p2, w2, b2, anc + 12, out, 20, 400, 24000, 32.f);
}

// Round 2
// 463.071 us; speedup vs baseline: 1.6284x; 1.6284x over previous
//
#include <hip/hip_runtime.h>
#include <math.h>

// YOLOv5 head as bf16 MFMA GEMM per scale:
//   y[o, b*hw] = sum_c w[o,c] * p[b,c,hw]; o in 0..254 (pad to 256), then
//   sigmoid+decode epilogue writing out[b, off + a*HW + hw, oo], o = a*85+oo.
// A (weights) pre-converted to bf16 [256][C] in d_ws once per launch; A-frags
// loaded straight from global (L2-hot). B staged fp32->bf16 through a 4KB LDS
// tile in MFMA B-frag layout ([n][k], 16B-chunk XOR swizzle).

#define NOUT 85
#define TOTAL_ROWS 25200

typedef __attribute__((ext_vector_type(8))) short short8;
typedef __attribute__((ext_vector_type(4))) float floatx4;

__device__ __forceinline__ unsigned short f2bf(float x) {
    union { float f; unsigned u; } v; v.f = x;
    unsigned r = v.u + 0x7fffu + ((v.u >> 16) & 1u);  // RNE
    return (unsigned short)(r >> 16);
}

// ws layout (ushort units): wA0 @ 0 (256*256), wA1 @ 65536 (256*512), wA2 @ 196608 (256*1024)
__global__ __launch_bounds__(256) void convert_w_all(
    const float* __restrict__ w0, const float* __restrict__ w1,
    const float* __restrict__ w2, unsigned short* __restrict__ dst)
{
    int i = blockIdx.x * 256 + threadIdx.x;   // 0 .. 458751
    const float* w; int C, idx;
    if (i < 65536)       { w = w0; C = 256;  idx = i; }
    else if (i < 196608) { w = w1; C = 512;  idx = i - 65536; }
    else                 { w = w2; C = 1024; idx = i - 196608; }
    int m = idx / C, c = idx - m * C;
    float v = (m < 255) ? w[(size_t)m * C + c] : 0.f;   // row 255 = zero pad
    dst[i] = f2bf(v);
}

template <int C>
__global__ __launch_bounds__(256) void yolo_mfma(
    const float* __restrict__ p,             // [16, C, HW]
    const unsigned short* __restrict__ wA,   // [256, C] bf16
    const float* __restrict__ bias,          // [255]
    const float* __restrict__ anchors,       // [3,2] this scale
    float* __restrict__ out,                 // [16, 25200, 85]
    int nx, int HW, int row_off, float stride_)
{
    __shared__ __align__(16) unsigned short Bl[64 * 32];  // [n][k] bf16, chunk-swizzled

    const int tid = threadIdx.x;
    const int l   = tid & 63;
    const int wv  = tid >> 6;          // wave id: M-stripe [64*wv, 64*wv+64)
    const int ml  = l & 15;
    const int q   = l >> 4;
    const int hw0 = blockIdx.x * 64;
    const int b   = blockIdx.y;

    floatx4 acc[4][4];
#pragma unroll
    for (int mi = 0; mi < 4; ++mi)
#pragma unroll
        for (int ni = 0; ni < 4; ++ni)
            acc[mi][ni] = floatx4{0.f, 0.f, 0.f, 0.f};

    const float* pb = p + (size_t)b * C * HW;

    // B staging assignment: thread handles column n=l, rows [wv*8, wv*8+8)
    const int sc0 = wv * 8;
    int scol = hw0 + l; if (scol >= HW) scol = HW - 1;   // clamp (scale2 tail)

    for (int k0 = 0; k0 < C; k0 += 32) {
        // global loads: 8 coalesced dwords down one p column
        float bv[8];
        const float* pcol = pb + (size_t)(k0 + sc0) * HW + scol;
#pragma unroll
        for (int r = 0; r < 8; ++r) bv[r] = pcol[(size_t)r * HW];

        // A-frags straight from global (row-major bf16, 16B contiguous)
        short8 af[4];
#pragma unroll
        for (int mi = 0; mi < 4; ++mi)
            af[mi] = *(const short8*)(wA + (size_t)(wv * 64 + mi * 16 + ml) * C + k0 + q * 8);

        unsigned pkd[4];
#pragma unroll
        for (int r = 0; r < 4; ++r)
            pkd[r] = (unsigned)f2bf(bv[2 * r]) | ((unsigned)f2bf(bv[2 * r + 1]) << 16);

        __syncthreads();   // prev iteration's frag reads done
        ((uint4*)Bl)[l * 4 + (wv ^ (l & 3))] = make_uint4(pkd[0], pkd[1], pkd[2], pkd[3]);
        __syncthreads();

        short8 bfr[4];
#pragma unroll
        for (int ni = 0; ni < 4; ++ni) {
            int n = ni * 16 + ml;
            bfr[ni] = *(const short8*)(Bl + n * 32 + (q ^ (n & 3)) * 8);
        }

#pragma unroll
        for (int mi = 0; mi < 4; ++mi)
#pragma unroll
            for (int ni = 0; ni < 4; ++ni)
                acc[mi][ni] = __builtin_amdgcn_mfma_f32_16x16x32_bf16(
                    af[mi], bfr[ni], acc[mi][ni], 0, 0, 0);
    }

    // Epilogue: D row = o = wv*64 + mi*16 + q*4 + r; col = hw = hw0 + ni*16 + ml
    const int obase0 = wv * 64 + q * 4;
#pragma unroll
    for (int mi = 0; mi < 4; ++mi) {
        const int obase = obase0 + mi * 16;
        int oo[4], aa[4]; float bi[4], an_w[4], an_h[4]; bool valid[4];
#pragma unroll
        for (int r = 0; r < 4; ++r) {
            int o = obase + r;
            valid[r] = (o < 255);
            int osafe = valid[r] ? o : 0;
            aa[r] = osafe / 85;
            oo[r] = osafe - aa[r] * 85;
            bi[r] = bias[osafe];
            an_w[r] = anchors[aa[r] * 2 + 0];
            an_h[r] = anchors[aa[r] * 2 + 1];
        }
#pragma unroll
        for (int ni = 0; ni < 4; ++ni) {
            int hw = hw0 + ni * 16 + ml;
            if (hw >= HW) continue;
            int gy = hw / nx;
            int gx = hw - gy * nx;
            size_t base = ((size_t)b * TOTAL_ROWS + row_off + hw) * NOUT;
#pragma unroll
            for (int r = 0; r < 4; ++r) {
                if (!valid[r]) continue;
                float y = acc[mi][ni][r] + bi[r];
                float s = 1.f / (1.f + __expf(-y));
                float v;
                if (oo[r] == 0)      v = (2.f * s + (float)gx - 0.5f) * stride_;
                else if (oo[r] == 1) v = (2.f * s + (float)gy - 0.5f) * stride_;
                else if (oo[r] == 2) { float t = 2.f * s; v = t * t * an_w[r]; }
                else if (oo[r] == 3) { float t = 2.f * s; v = t * t * an_h[r]; }
                else                 v = s;
                out[base + (size_t)aa[r] * HW * NOUT + oo[r]] = v;
            }
        }
    }
}

extern "C" void kernel_launch(void* const* d_in, const int* in_sizes, int n_in,
                              void* d_out, int out_size, void* d_ws, size_t ws_size,
                              hipStream_t stream) {
    const float* p0 = (const float*)d_in[0];
    const float* p1 = (const float*)d_in[1];
    const float* p2 = (const float*)d_in[2];
    const float* w0 = (const float*)d_in[3];
    const float* b0 = (const float*)d_in[4];
    const float* w1 = (const float*)d_in[5];
    const float* b1 = (const float*)d_in[6];
    const float* w2 = (const float*)d_in[7];
    const float* b2 = (const float*)d_in[8];
    const float* anc = (const float*)d_in[9];  // [3,3,2]
    float* out = (float*)d_out;

    unsigned short* wsA = (unsigned short*)d_ws;   // needs 917504 B

    convert_w_all<<<dim3(458752 / 256), dim3(256), 0, stream>>>(w0, w1, w2, wsA);

    const int bs = 16;
    // scale 0: C=256, HW=6400 (80x80), stride 8
    yolo_mfma<256><<<dim3(100, bs), dim3(256), 0, stream>>>(
        p0, wsA + 0, b0, anc + 0, out, 80, 6400, 0, 8.f);
    // scale 1: C=512, HW=1600 (40x40), stride 16
    yolo_mfma<512><<<dim3(25, bs), dim3(256), 0, stream>>>(
        p1, wsA + 65536, b1, anc + 6, out, 40, 1600, 19200, 16.f);
    // scale 2: C=1024, HW=400 (20x20), stride 32 — 7 N-tiles (last partial)
    yolo_mfma<1024><<<dim3(7, bs), dim3(256), 0, stream>>>(
        p2, wsA + 196608, b2, anc + 12, out, 20, 400, 24000, 32.f);
}